// Round 3
// baseline (370.038 us; speedup 1.0000x reference)
//
#include <hip/hip_runtime.h>

#define BB 16
#define TT 2048
#define NROW 513
#define HOP 256
#define OUTLB 524288          // out length per batch
#define FTO 28                // output frames per block
#define SPAN (FTO*HOP)        // 7168
#define TILES 74              // ceil(2048/28)
#define RZ2 514               // zc row stride in float2; 514 mod 16 == 2 (bank rotation)

// reverse the three octal digits of a 9-bit index (radix-8 DIT input order)
__device__ __forceinline__ int dig8rev(int k){ return ((k&7)<<6) | (k&56) | (k>>6); }
// swizzle: fold m[5:3]^m[8:6] into m[2:0]; with row stride ≡2 mod 16 this puts
// every FFT-stage / storeZ / gather access at the b64 minimum of 4 lanes per
// bank-pair (verified per-pattern by hand; old ttab strided reads were 16-way)
__device__ __forceinline__ int zidx(int f,int m){ return f*RZ2 + (m ^ ((m>>3)&7) ^ ((m>>6)&7)); }

#define CADD(a,b) make_float2((a).x+(b).x,(a).y+(b).y)
#define CSUB(a,b) make_float2((a).x-(b).x,(a).y-(b).y)

// 8-point DFT, positive exponent (inverse-FFT convention), in place.
__device__ __forceinline__ void dft8(float2 (&y)[8]){
  const float C7 = 0.70710678118654752f;
  float2 s0=CADD(y[0],y[4]), s1=CSUB(y[0],y[4]);
  float2 s2=CADD(y[2],y[6]), s3=CSUB(y[2],y[6]);
  float2 u0=CADD(y[1],y[5]), u1=CSUB(y[1],y[5]);
  float2 u2=CADD(y[3],y[7]), u3=CSUB(y[3],y[7]);
  float2 E0=CADD(s0,s2), E2=CSUB(s0,s2);
  float2 E1=make_float2(s1.x - s3.y, s1.y + s3.x);
  float2 E3=make_float2(s1.x + s3.y, s1.y - s3.x);
  float2 O0=CADD(u0,u2), O2=CSUB(u0,u2);
  float2 O1=make_float2(u1.x - u3.y, u1.y + u3.x);
  float2 O3=make_float2(u1.x + u3.y, u1.y - u3.x);
  float2 T1=make_float2(C7*(O1.x-O1.y), C7*(O1.x+O1.y));   // W8^1 * O1
  float2 T2=make_float2(-O2.y, O2.x);                      // i * O2
  float2 T3=make_float2(C7*(-O3.x-O3.y), C7*(O3.x-O3.y));  // W8^3 * O3
  y[0]=CADD(E0,O0); y[4]=CSUB(E0,O0);
  y[1]=CADD(E1,T1); y[5]=CSUB(E1,T1);
  y[2]=CADD(E2,T2); y[6]=CSUB(E2,T2);
  y[3]=CADD(E3,T3); y[7]=CSUB(E3,T3);
}

// (512,4): VGPR budget = floor(256/min_waves) -> 64 here; (512,6)/(512,8)
// force 40/32-VGPR budgets -> mass spills (measured +174/+252MB FETCH).
__global__ __launch_bounds__(512,4) void istft_fused(
    const float* __restrict__ sr, const float* __restrict__ si,
    const float* __restrict__ win, float* __restrict__ out)
{
  __shared__ float2 zc[8*RZ2];                      // 32896 B
  __shared__ float2 wtab[512];                      // 4096 B => 36992 B total

  const int tid  = threadIdx.x;
  const int b    = blockIdx.x / TILES;
  const int tile = blockIdx.x % TILES;
  const int Tbase= tile*FTO - 2;

  wtab[tid] = ((const float2*)win)[tid];            // (w[2m], w[2m+1])

  float2 acc[7];                                    // 7 output pairs per thread
  #pragma unroll
  for (int i=0;i<7;++i) acc[i]=make_float2(0.f,0.f);

  const int f  = tid & 7;                           // frame slot within chunk
  const int pp = tid >> 3;                          // [0,64)
  const float* srb = sr + (size_t)b*NROW*TT;
  const float* sib = si + (size_t)b*NROW*TT;

  auto storeZ = [&](int cc, float ar,float ai,float br,float bi,float cr,float ci){
    int k = cc*64+pp;
    if (k==0){
      zc[zidx(f,0)] = make_float2(0.5f*(ar+br), 0.5f*(ar-br));
      zc[zidx(f,4)] = make_float2(cr, -ci);         // dig8rev(256)=4, Z=conj(X[256])
    } else {
      float s_,c_; __sincosf((float)k*0.006135923151542565f,&s_,&c_);  // e^{i*pi*k/512}
      float Er=0.5f*(ar+br), Ei=0.5f*(ai-bi);
      float Dr=0.5f*(ar-br), Di=0.5f*(ai+bi);
      float Or=Dr*c_-Di*s_, Oi=Dr*s_+Di*c_;
      zc[zidx(f,dig8rev(k))]     = make_float2(Er-Oi, Ei+Or);
      zc[zidx(f,dig8rev(512-k))] = make_float2(Er+Oi, Or-Ei);
    }
  };

  // 512-pt FFT as 3 radix-8 DIT stages (input digit-reversed, output natural).
  // One 8-pt butterfly per thread per stage per frame; in-place (disjoint octets);
  // 1 barrier per stage. Twiddles on the fly (stage 0 is twiddle-free).
  auto do_fft = [&](){
    float2 y[8];
    // ---- stage 0: h=1
    __syncthreads();
    {
      const int base = pp<<3;
      #pragma unroll
      for (int t=0;t<8;++t) y[t]=zc[zidx(f,base+t)];
      dft8(y);
      #pragma unroll
      for (int t=0;t<8;++t) zc[zidx(f,base+t)]=y[t];
    }
    // ---- stage 1: h=8, twiddle W_64^{ilo*t}
    __syncthreads();
    {
      const int ilo = pp&7, base = ((pp>>3)<<6) + ilo;
      #pragma unroll
      for (int t=0;t<8;++t) y[t]=zc[zidx(f,base+8*t)];
      const float a1 = (float)ilo * 0.09817477042468103f;   // 2*pi/64
      #pragma unroll
      for (int t=1;t<8;++t){
        float s_,c_; __sincosf(a1*(float)t,&s_,&c_);
        float xr=y[t].x, xi=y[t].y;
        y[t]=make_float2(xr*c_-xi*s_, xr*s_+xi*c_);
      }
      dft8(y);
      #pragma unroll
      for (int t=0;t<8;++t) zc[zidx(f,base+8*t)]=y[t];
    }
    // ---- stage 2: h=64, twiddle W_512^{pp*t}
    __syncthreads();
    {
      #pragma unroll
      for (int t=0;t<8;++t) y[t]=zc[zidx(f,pp+64*t)];
      const float a2 = (float)pp * 0.012271846303085130f;   // 2*pi/512
      #pragma unroll
      for (int t=1;t<8;++t){
        float s_,c_; __sincosf(a2*(float)t,&s_,&c_);
        float xr=y[t].x, xi=y[t].y;
        y[t]=make_float2(xr*c_-xi*s_, xr*s_+xi*c_);
      }
      dft8(y);
      #pragma unroll
      for (int t=0;t<8;++t) zc[zidx(f,pp+64*t)]=y[t];
    }
  };

  // register-gather OLA: thread owns pairs p0 = 2*(tid+512i); contributions
  // from slots s with j0-256s in [0,1024), j0 = p0 + 896 - 2048c (masked
  // frames are zero in zc, so no validity checks needed)
  auto do_gather = [&](int c){
    __syncthreads();
    const int jb = 896 - 2048*c;
    #pragma unroll
    for (int i=0;i<7;++i){
      int j0 = 2*(tid + 512*i) + jb;                // even
      int s_lo = max(0, (j0-768)>>8);
      int s_hi = min(7, j0>>8);
      for (int s=s_lo; s<=s_hi; ++s){
        int m0 = (j0 - 256*s)>>1;                   // [0,512), even j0 => exact
        float2 v = zc[zidx(s,m0)];
        float2 w = wtab[m0];
        acc[i].x += v.x*w.x;
        acc[i].y += v.y*w.y;
      }
    }
  };

  // ---- main: 2 chunk-pairs; pair loads issued back-to-back (full 64B lines) ----
  for (int half=0; half<2; ++half){
    const int c0  = 2*half;
    const int ta  = Tbase + 8*c0 + f;
    const int tb_ = ta + 8;
    const int tca = min(max(ta ,0),TT-1);
    const int tcb = min(max(tb_,0),TT-1);
    const float ma  = (ta >=0 && ta <TT)?(1.f/512.f):0.f;   // fold 1/512 scale
    const float mb2 = (tb_>=0 && tb_<TT)?(1.f/512.f):0.f;

    float sAr[4],sAi[4],sBr[4],sBi[4];              // stash for chunk c0+1
    float sCr=0.f, sCi=0.f;

    __syncthreads();                                // zc WAR vs prev gather
    #pragma unroll
    for (int cc=0;cc<4;++cc){
      int k = cc*64+pp;                             // [0,256)
      const float* pr  = srb + (size_t)k*TT;
      const float* pi_ = sib + (size_t)k*TT;
      const float* qr  = srb + (size_t)(512-k)*TT;
      const float* qi  = sib + (size_t)(512-k)*TT;
      float ar0=pr [tca], ar1=pr [tcb];             // adjacent halves of one line
      float ai0=pi_[tca], ai1=pi_[tcb];
      float br0=qr [tca], br1=qr [tcb];
      float bi0=qi [tca], bi1=qi [tcb];
      sAr[cc]=ar1; sAi[cc]=ai1; sBr[cc]=br1; sBi[cc]=bi1;
      float cr0=0.f, ci0=0.f;
      if (cc==0 && pp==0){                          // k==0 thread: X[256] too
        const float* rr = srb + (size_t)256*TT;
        const float* ri = sib + (size_t)256*TT;
        cr0 = rr[tca]; sCr = rr[tcb];
        ci0 = ri[tca]; sCi = ri[tcb];
      }
      storeZ(cc, ar0*ma, ai0*ma, br0*ma, bi0*ma, cr0*ma, ci0*ma);
    }
    do_fft();
    do_gather(c0);

    __syncthreads();                                // zc WAR
    #pragma unroll
    for (int cc=0;cc<4;++cc){
      storeZ(cc, sAr[cc]*mb2, sAi[cc]*mb2, sBr[cc]*mb2, sBi[cc]*mb2, sCr*mb2, sCi*mb2);
    }
    do_fft();
    do_gather(c0+1);
  }

  // ---- finalize from registers: env division (1.5 interior), float2 store ----
  const bool edge = (tile==0)|(tile==TILES-1);
  float* outb = out + (size_t)b*OUTLB;
  const int gbase = tile*SPAN;
  #pragma unroll
  for (int i=0;i<7;++i){
    int p0 = 2*(tid + 512*i);
    int gs = gbase + p0;
    if (gs < OUTLB){
      float2 r = acc[i];
      if (!edge){
        r.x *= (2.f/3.f); r.y *= (2.f/3.f);         // Hann 4x OLA env = 1.5
      } else {
        #pragma unroll
        for (int e=0;e<2;++e){
          int l = gbase + 384 + p0 + e;
          int j0 = l & 255, tb = l >> 8;
          float env=0.f;
          #pragma unroll
          for (int mm=0;mm<4;++mm){
            int t2 = tb-mm;
            if (t2>=0 && t2<TT){
              float wv = 0.5f-0.5f*__cosf((float)(j0+256*mm)*0.006135923151542565f);
              env += wv*wv;
            }
          }
          ((float*)&r)[e] /= env;
        }
      }
      *(float2*)(outb+gs) = r;
    }
  }
}

extern "C" void kernel_launch(void* const* d_in, const int* in_sizes, int n_in,
                              void* d_out, int out_size, void* d_ws, size_t ws_size,
                              hipStream_t stream) {
  const float* sr = (const float*)d_in[0];
  const float* si = (const float*)d_in[1];
  const float* w  = (const float*)d_in[2];
  float* out = (float*)d_out;
  istft_fused<<<BB*TILES, 512, 0, stream>>>(sr, si, w, out);
}

// Round 4
// 332.487 us; speedup vs baseline: 1.1129x; 1.1129x over previous
//
#include <hip/hip_runtime.h>

#define BB 16
#define TT 2048
#define NROW 513
#define HOP 256
#define OUTLB 524288          // out length per batch
#define FTO 28                // output frames per block
#define SPAN (FTO*HOP)        // 7168
#define TILES 74              // ceil(2048/28)
#define RZ2 514               // zc row stride in float2; 514 mod 16 == 2 (bank rotation)

// reverse the three octal digits of a 9-bit index (radix-8 DIT input order)
__device__ __forceinline__ int dig8rev(int k){ return ((k&7)<<6) | (k&56) | (k>>6); }
// swizzle: fold m[5:3]^m[8:6] into m[2:0]; with row stride ≡2 mod 16 every
// FFT-stage / storeZ / gather access sits at the b64 minimum banking.
// (verified: round-3 cut SQ_LDS_BANK_CONFLICT 1.14e7 -> 1.95e6, correct output)
__device__ __forceinline__ int zidx(int f,int m){ return f*RZ2 + (m ^ ((m>>3)&7) ^ ((m>>6)&7)); }

#define CADD(a,b) make_float2((a).x+(b).x,(a).y+(b).y)
#define CSUB(a,b) make_float2((a).x-(b).x,(a).y-(b).y)

// 8-point DFT, positive exponent (inverse-FFT convention), in place.
__device__ __forceinline__ void dft8(float2 (&y)[8]){
  const float C7 = 0.70710678118654752f;
  float2 s0=CADD(y[0],y[4]), s1=CSUB(y[0],y[4]);
  float2 s2=CADD(y[2],y[6]), s3=CSUB(y[2],y[6]);
  float2 u0=CADD(y[1],y[5]), u1=CSUB(y[1],y[5]);
  float2 u2=CADD(y[3],y[7]), u3=CSUB(y[3],y[7]);
  float2 E0=CADD(s0,s2), E2=CSUB(s0,s2);
  float2 E1=make_float2(s1.x - s3.y, s1.y + s3.x);
  float2 E3=make_float2(s1.x + s3.y, s1.y - s3.x);
  float2 O0=CADD(u0,u2), O2=CSUB(u0,u2);
  float2 O1=make_float2(u1.x - u3.y, u1.y + u3.x);
  float2 O3=make_float2(u1.x + u3.y, u1.y - u3.x);
  float2 T1=make_float2(C7*(O1.x-O1.y), C7*(O1.x+O1.y));   // W8^1 * O1
  float2 T2=make_float2(-O2.y, O2.x);                      // i * O2
  float2 T3=make_float2(C7*(-O3.x-O3.y), C7*(O3.x-O3.y));  // W8^3 * O3
  y[0]=CADD(E0,O0); y[4]=CSUB(E0,O0);
  y[1]=CADD(E1,T1); y[5]=CSUB(E1,T1);
  y[2]=CADD(E2,T2); y[6]=CSUB(E2,T2);
  y[3]=CADD(E3,T3); y[7]=CSUB(E3,T3);
}

// (512,4): VGPR budget = floor(256/min_waves) = 64 (measured; (512,6)/(512,8)
// force 40/32 -> mass spills). Round-3 radix-8 spilled at 64 because the
// 18-reg line-half stash + y[8] exceeded the cap; this version DROPS the stash
// (each chunk reloads its 32B half; line fetched one chunk earlier -> L2 hit),
// keeping live set ~50 regs. Same global-load instruction count as baseline.
__global__ __launch_bounds__(512,4) void istft_fused(
    const float* __restrict__ sr, const float* __restrict__ si,
    const float* __restrict__ win, float* __restrict__ out)
{
  __shared__ float2 zc[8*RZ2];                      // 32896 B
  __shared__ float2 wtab[512];                      // 4096 B => 36992 B total

  const int tid  = threadIdx.x;
  const int b    = blockIdx.x / TILES;
  const int tile = blockIdx.x % TILES;
  const int Tbase= tile*FTO - 2;

  wtab[tid] = ((const float2*)win)[tid];            // (w[2m], w[2m+1])

  float2 acc[7];                                    // 7 output pairs per thread
  #pragma unroll
  for (int i=0;i<7;++i) acc[i]=make_float2(0.f,0.f);

  const int f  = tid & 7;                           // frame slot within chunk
  const int pp = tid >> 3;                          // [0,64)
  const float* srb = sr + (size_t)b*NROW*TT;
  const float* sib = si + (size_t)b*NROW*TT;

  auto storeZ = [&](int cc, float ar,float ai,float br,float bi,float cr,float ci){
    int k = cc*64+pp;
    if (k==0){
      zc[zidx(f,0)] = make_float2(0.5f*(ar+br), 0.5f*(ar-br));
      zc[zidx(f,4)] = make_float2(cr, -ci);         // dig8rev(256)=4, Z=conj(X[256])
    } else {
      float s_,c_; __sincosf((float)k*0.006135923151542565f,&s_,&c_);  // e^{i*pi*k/512}
      float Er=0.5f*(ar+br), Ei=0.5f*(ai-bi);
      float Dr=0.5f*(ar-br), Di=0.5f*(ai+bi);
      float Or=Dr*c_-Di*s_, Oi=Dr*s_+Di*c_;
      zc[zidx(f,dig8rev(k))]     = make_float2(Er-Oi, Ei+Or);
      zc[zidx(f,dig8rev(512-k))] = make_float2(Er+Oi, Or-Ei);
    }
  };

  // 512-pt FFT as 3 radix-8 DIT stages (input digit-reversed, output natural).
  // One 8-pt butterfly per thread per stage per frame; in-place (disjoint octets);
  // 1 barrier per stage. Twiddles on the fly (stage 0 is twiddle-free).
  auto do_fft = [&](){
    float2 y[8];
    // ---- stage 0: h=1
    __syncthreads();
    {
      const int base = pp<<3;
      #pragma unroll
      for (int t=0;t<8;++t) y[t]=zc[zidx(f,base+t)];
      dft8(y);
      #pragma unroll
      for (int t=0;t<8;++t) zc[zidx(f,base+t)]=y[t];
    }
    // ---- stage 1: h=8, twiddle W_64^{ilo*t}
    __syncthreads();
    {
      const int ilo = pp&7, base = ((pp>>3)<<6) + ilo;
      #pragma unroll
      for (int t=0;t<8;++t) y[t]=zc[zidx(f,base+8*t)];
      const float a1 = (float)ilo * 0.09817477042468103f;   // 2*pi/64
      #pragma unroll
      for (int t=1;t<8;++t){
        float s_,c_; __sincosf(a1*(float)t,&s_,&c_);
        float xr=y[t].x, xi=y[t].y;
        y[t]=make_float2(xr*c_-xi*s_, xr*s_+xi*c_);
      }
      dft8(y);
      #pragma unroll
      for (int t=0;t<8;++t) zc[zidx(f,base+8*t)]=y[t];
    }
    // ---- stage 2: h=64, twiddle W_512^{pp*t}
    __syncthreads();
    {
      #pragma unroll
      for (int t=0;t<8;++t) y[t]=zc[zidx(f,pp+64*t)];
      const float a2 = (float)pp * 0.012271846303085130f;   // 2*pi/512
      #pragma unroll
      for (int t=1;t<8;++t){
        float s_,c_; __sincosf(a2*(float)t,&s_,&c_);
        float xr=y[t].x, xi=y[t].y;
        y[t]=make_float2(xr*c_-xi*s_, xr*s_+xi*c_);
      }
      dft8(y);
      #pragma unroll
      for (int t=0;t<8;++t) zc[zidx(f,pp+64*t)]=y[t];
    }
  };

  // register-gather OLA: thread owns pairs p0 = 2*(tid+512i); contributions
  // from slots s with j0-256s in [0,1024), j0 = p0 + 896 - 2048c (masked
  // frames are zero in zc, so no validity checks needed)
  auto do_gather = [&](int c){
    __syncthreads();
    const int jb = 896 - 2048*c;
    #pragma unroll
    for (int i=0;i<7;++i){
      int j0 = 2*(tid + 512*i) + jb;                // even
      int s_lo = max(0, (j0-768)>>8);
      int s_hi = min(7, j0>>8);
      for (int s=s_lo; s<=s_hi; ++s){
        int m0 = (j0 - 256*s)>>1;                   // [0,512), even j0 => exact
        float2 v = zc[zidx(s,m0)];
        float2 w = wtab[m0];
        acc[i].x += v.x*w.x;
        acc[i].y += v.y*w.y;
      }
    }
  };

  // ---- main: 4 chunks, each stages its own 32B line-halves (no reg stash;
  // the other half of each 64B line is read by the adjacent chunk -> L2 hit) ----
  for (int c=0; c<4; ++c){
    const int ta  = Tbase + 8*c + f;
    const int tca = min(max(ta,0),TT-1);
    const float ma = (ta>=0 && ta<TT)?(1.f/512.f):0.f;      // fold 1/512 scale

    __syncthreads();                                // zc WAR vs prev gather
    #pragma unroll
    for (int cc=0;cc<4;++cc){
      int k = cc*64+pp;                             // [0,256)
      const float* pr  = srb + (size_t)k*TT;
      const float* pi_ = sib + (size_t)k*TT;
      const float* qr  = srb + (size_t)(512-k)*TT;
      const float* qi  = sib + (size_t)(512-k)*TT;
      float ar0=pr [tca];
      float ai0=pi_[tca];
      float br0=qr [tca];
      float bi0=qi [tca];
      float cr0=0.f, ci0=0.f;
      if (cc==0 && pp==0){                          // k==0 thread: X[256] too
        cr0 = srb[(size_t)256*TT + tca];
        ci0 = sib[(size_t)256*TT + tca];
      }
      storeZ(cc, ar0*ma, ai0*ma, br0*ma, bi0*ma, cr0*ma, ci0*ma);
    }
    do_fft();
    do_gather(c);
  }

  // ---- finalize from registers: env division (1.5 interior), float2 store ----
  const bool edge = (tile==0)|(tile==TILES-1);
  float* outb = out + (size_t)b*OUTLB;
  const int gbase = tile*SPAN;
  #pragma unroll
  for (int i=0;i<7;++i){
    int p0 = 2*(tid + 512*i);
    int gs = gbase + p0;
    if (gs < OUTLB){
      float2 r = acc[i];
      if (!edge){
        r.x *= (2.f/3.f); r.y *= (2.f/3.f);         // Hann 4x OLA env = 1.5
      } else {
        #pragma unroll
        for (int e=0;e<2;++e){
          int l = gbase + 384 + p0 + e;
          int j0 = l & 255, tb = l >> 8;
          float env=0.f;
          #pragma unroll
          for (int mm=0;mm<4;++mm){
            int t2 = tb-mm;
            if (t2>=0 && t2<TT){
              float wv = 0.5f-0.5f*__cosf((float)(j0+256*mm)*0.006135923151542565f);
              env += wv*wv;
            }
          }
          ((float*)&r)[e] /= env;
        }
      }
      *(float2*)(outb+gs) = r;
    }
  }
}

extern "C" void kernel_launch(void* const* d_in, const int* in_sizes, int n_in,
                              void* d_out, int out_size, void* d_ws, size_t ws_size,
                              hipStream_t stream) {
  const float* sr = (const float*)d_in[0];
  const float* si = (const float*)d_in[1];
  const float* w  = (const float*)d_in[2];
  float* out = (float*)d_out;
  istft_fused<<<BB*TILES, 512, 0, stream>>>(sr, si, w, out);
}

// Round 6
// 278.829 us; speedup vs baseline: 1.3271x; 1.1924x over previous
//
#include <hip/hip_runtime.h>

#define BB 16
#define TT 2048
#define NROW 513
#define HOP 256
#define OUTLB 524288          // out length per batch
#define FTO 28                // output frames per block
#define SPAN (FTO*HOP)        // 7168
#define TILES 74              // ceil(2048/28)
#define NWG (BB*TILES)        // 1184 = 8*148 -> exact chunked XCD swizzle
#define CPX (NWG/8)           // 148 consecutive logical blocks per XCD

__device__ __forceinline__ int brev9(int k){ return (int)(__brev((unsigned)k)>>23); }
// bank swizzle: fold m[5:3]^m[8:6] into m[2:0] (r3/r4 measured: conflicts
// 1.14e7 -> 1.95e6); row stride is now 512 (bank-neutral) so the per-row
// rotation is an explicit XOR of (2*row mod 16). Bijective per row; every
// access pattern (staging scatter / radix-4 stages / radix-2 / gather)
// hand-checked at the 4-lanes-per-bank-pair wave64 minimum.
__device__ __forceinline__ int zidx(int r,int m){
  int s = m ^ ((m>>3)&7) ^ ((m>>6)&7);
  return (r<<9) + (s ^ ((2*r)&15));
}

// (512,4): VGPR budget = floor(256/min_waves) = 64 (measured; (512,6)/(512,8)
// force 40/32 -> mass spills). Radix-4 keeps peak live ~50 regs (radix-8's
// y[8] spilled ~89MB in r4). LDS = 16*512*8 = 65536 B STATIC (no dynamic-LDS
// attribute call: host-side hipFuncSetAttribute inside kernel_launch broke
// graph capture in r5). 2 blocks/CU by LDS.
__global__ __launch_bounds__(512,4) void istft_fused(
    const float* __restrict__ sr, const float* __restrict__ si,
    const float* __restrict__ win, float* __restrict__ out)
{
  __shared__ float2 zc[16*512];                    // 65536 B: frames T0..T0+15

  const int tid = threadIdx.x;
  // chunked XCD swizzle: dispatch d -> logical L so each XCD owns 148
  // CONSECUTIVE (b,tile) ids; straddled cache lines and the 4-frame tile
  // overlap are then re-read by same-XCD neighbors -> L2 hits, not HBM.
  const int d    = blockIdx.x;
  const int L    = (d & 7)*CPX + (d >> 3);
  const int b    = L / TILES;
  const int tile = L % TILES;
  const int Tbase= tile*FTO - 2;

  float2 acc[7];                                   // 7 output pairs per thread
  #pragma unroll
  for (int i=0;i<7;++i) acc[i]=make_float2(0.f,0.f);

  const int f  = tid & 7;                          // t-pair slot / frame slot
  const int pp = tid >> 3;                         // [0,64)
  const float* srb = sr + (size_t)b*NROW*TT;
  const float* sib = si + (size_t)b*NROW*TT;

  // Per-thread window registers: in the gather, m0 == (tid+64) mod 128 for
  // every (i,half,S), so this thread only ever needs 4 window float2 pairs.
  // Statically indexed (j) -> stays in registers. Coalesced 512B/wave load.
  const int r_w = (tid + 64) & 127;
  float2 wreg[4];
  #pragma unroll
  for (int j=0;j<4;++j) wreg[j] = ((const float2*)win)[r_w + 128*j];

  // build Z[row] entries for one frame (row in [0,16)) from spectrum row k
  auto storeZ = [&](int row, int k, float ar,float ai,float br,float bi,
                    float cr,float ci, float s_, float c_){
    if (k==0){
      zc[zidx(row,0)] = make_float2(0.5f*(ar+br), 0.5f*(ar-br));
      zc[zidx(row,1)] = make_float2(cr, -ci);      // brev9(256)=1, Z=conj(X[256])
    } else {
      float Er=0.5f*(ar+br), Ei=0.5f*(ai-bi);
      float Dr=0.5f*(ar-br), Di=0.5f*(ai+bi);
      float Or=Dr*c_-Di*s_, Oi=Dr*s_+Di*c_;
      zc[zidx(row,brev9(k))]     = make_float2(Er-Oi, Ei+Or);
      zc[zidx(row,brev9(512-k))] = make_float2(Er+Oi, Or-Ei);
    }
  };

  for (int half=0; half<2; ++half){
    const int T0 = Tbase + 16*half;
    const int ta = T0 + 2*f;                       // even
    const int tp = min(max(ta,0),TT-2);            // clamped, even -> 8B aligned
    const float m0_ = (ta>=0   && ta  <TT)?(1.f/512.f):0.f;
    const float m1_ = (ta+1>=0 && ta+1<TT)?(1.f/512.f):0.f;

    __syncthreads();                               // zc WAR vs previous gather
    #pragma unroll
    for (int cc=0;cc<4;++cc){
      const int k = cc*64+pp;                      // [0,256)
      // float2 loads: 8 lanes x 8B = full 64B row segment consumed at once
      const float2 vRk = *(const float2*)(srb + (size_t)k*TT + tp);
      const float2 vIk = *(const float2*)(sib + (size_t)k*TT + tp);
      const float2 vRq = *(const float2*)(srb + (size_t)(512-k)*TT + tp);
      const float2 vIq = *(const float2*)(sib + (size_t)(512-k)*TT + tp);
      float2 vRc=make_float2(0.f,0.f), vIc=make_float2(0.f,0.f);
      if (cc==0 && pp==0){                         // k==0 thread: X[256] too
        vRc = *(const float2*)(srb + (size_t)256*TT + tp);
        vIc = *(const float2*)(sib + (size_t)256*TT + tp);
      }
      float s_,c_; __sincosf((float)k*0.006135923151542565f,&s_,&c_);  // e^{i*pi*k/512}
      storeZ(2*f,   k, vRk.x*m0_, vIk.x*m0_, vRq.x*m0_, vIq.x*m0_, vRc.x*m0_, vIc.x*m0_, s_, c_);
      storeZ(2*f+1, k, vRk.y*m1_, vIk.y*m1_, vRq.y*m1_, vIq.y*m1_, vRc.y*m1_, vIc.y*m1_, s_, c_);
    }

    // 512-pt FFT on both 8-row chunks between the same barriers
    // (4 radix-4 stages + radix-2; twiddles on the fly, shared across chunks)
    #pragma unroll
    for (int st=0; st<4; ++st){
      __syncthreads();
      const int h = 1<<(2*st);
      #pragma unroll
      for (int i=0;i<2;++i){
        const int q   = pp + 64*i;                 // [0,128)
        const int ilo = q & (h-1);
        const int base= ((q>>(2*st))<<(2*st+2)) + ilo;
        float2 w1, w2;
        if (st==0){ w1=make_float2(1.f,0.f); w2=w1; }
        else {
          float s1,c1,s2,c2;
          __sincosf((float)(ilo<<(8-2*st))*0.012271846303085130f,&s1,&c1);
          __sincosf((float)(ilo<<(7-2*st))*0.012271846303085130f,&s2,&c2);
          w1=make_float2(c1,s1); w2=make_float2(c2,s2);
        }
        #pragma unroll
        for (int ch=0; ch<2; ++ch){
          const int r = ch*8 + f;
          float2 e0=zc[zidx(r,base)],     e1=zc[zidx(r,base+h)];
          float2 e2=zc[zidx(r,base+2*h)], e3=zc[zidx(r,base+3*h)];
          float t1r=e1.x*w1.x-e1.y*w1.y, t1i=e1.x*w1.y+e1.y*w1.x;
          float t3r=e3.x*w1.x-e3.y*w1.y, t3i=e3.x*w1.y+e3.y*w1.x;
          float arr=e0.x+t1r, ari=e0.y+t1i, brr=e0.x-t1r, bri=e0.y-t1i;
          float crr=e2.x+t3r, cri=e2.y+t3i, drr=e2.x-t3r, dri=e2.y-t3i;
          float cwr=crr*w2.x-cri*w2.y, cwi=crr*w2.y+cri*w2.x;
          float dwr=drr*w2.x-dri*w2.y, dwi=drr*w2.y+dri*w2.x;
          zc[zidx(r,base)]     = make_float2(arr+cwr, ari+cwi);
          zc[zidx(r,base+2*h)] = make_float2(arr-cwr, ari-cwi);
          zc[zidx(r,base+h)]   = make_float2(brr-dwi, bri+dwr);  // W^128=+i
          zc[zidx(r,base+3*h)] = make_float2(brr+dwi, bri-dwr);
        }
      }
    }
    __syncthreads();
    #pragma unroll
    for (int i=0;i<4;++i){                         // final radix-2, h=256
      const int q = pp + 64*i;                     // [0,256)
      float sq,cq; __sincosf((float)q*0.012271846303085130f,&sq,&cq);
      #pragma unroll
      for (int ch=0; ch<2; ++ch){
        const int r = ch*8 + f;
        float2 u = zc[zidx(r,q)], v = zc[zidx(r,q+256)];
        float tr=v.x*cq-v.y*sq, ti=v.x*sq+v.y*cq;
        zc[zidx(r,q)]     = make_float2(u.x+tr, u.y+ti);
        zc[zidx(r,q+256)] = make_float2(u.x-tr, u.y-ti);
      }
    }

    // merged register-gather OLA over all 16 staged frames.
    // m0 = base - 128*S with base = tid+512i+448-2048*half; base == r_w mod 128,
    // so m0 = r_w + 128*j and S = Sb - j, j=0..3 static (window from wreg[j]).
    __syncthreads();
    const int boff = 448 - 2048*half;
    #pragma unroll
    for (int i=0;i<7;++i){
      const int base = tid + 512*i + boff;
      const int Sb   = (base - r_w) >> 7;          // exact (base == r_w mod 128)
      #pragma unroll
      for (int j=0;j<4;++j){
        const int S = Sb - j;
        if (S >= 0 && S < 16){
          const int m0 = r_w + 128*j;              // [0,512)
          float2 v = zc[zidx(S,m0)];
          acc[i].x += v.x*wreg[j].x;
          acc[i].y += v.y*wreg[j].y;
        }
      }
    }
  }

  // ---- finalize from registers: env division (1.5 interior), float2 store ----
  const bool edge = (tile==0)|(tile==TILES-1);
  float* outb = out + (size_t)b*OUTLB;
  const int gbase = tile*SPAN;
  #pragma unroll
  for (int i=0;i<7;++i){
    int p0 = 2*(tid + 512*i);
    int gs = gbase + p0;
    if (gs < OUTLB){
      float2 r = acc[i];
      if (!edge){
        r.x *= (2.f/3.f); r.y *= (2.f/3.f);        // Hann 4x OLA env = 1.5
      } else {
        #pragma unroll
        for (int e=0;e<2;++e){
          int l = gbase + 384 + p0 + e;
          int j0 = l & 255, tb = l >> 8;
          float env=0.f;
          #pragma unroll
          for (int mm=0;mm<4;++mm){
            int t2 = tb-mm;
            if (t2>=0 && t2<TT){
              float wv = 0.5f-0.5f*__cosf((float)(j0+256*mm)*0.006135923151542565f);
              env += wv*wv;
            }
          }
          ((float*)&r)[e] /= env;
        }
      }
      *(float2*)(outb+gs) = r;
    }
  }
}

extern "C" void kernel_launch(void* const* d_in, const int* in_sizes, int n_in,
                              void* d_out, int out_size, void* d_ws, size_t ws_size,
                              hipStream_t stream) {
  const float* sr = (const float*)d_in[0];
  const float* si = (const float*)d_in[1];
  const float* w  = (const float*)d_in[2];
  float* out = (float*)d_out;
  istft_fused<<<NWG, 512, 0, stream>>>(sr, si, w, out);
}

// Round 7
// 253.821 us; speedup vs baseline: 1.4579x; 1.0985x over previous
//
#include <hip/hip_runtime.h>

#define BB 16
#define TT 2048
#define NROW 513
#define HOP 256
#define OUTLB 524288          // out length per batch
#define FTO 28                // output frames per block
#define SPAN (FTO*HOP)        // 7168
#define TILES 74              // ceil(2048/28)
#define NWG (BB*TILES)        // 1184 = 8*148 -> exact chunked XCD swizzle
#define CPX (NWG/8)           // 148 consecutive logical blocks per XCD

__device__ __forceinline__ int brev9(int k){ return (int)(__brev((unsigned)k)>>23); }
// bank swizzle: fold m[5:3]^m[8:6] into m[2:0], rotate by (2*row mod 16).
// Measured r6: SQ_LDS_BANK_CONFLICT 4.6e6 vs 1.14e7 for unswizzled radix-4 (r0).
__device__ __forceinline__ int zidx(int r,int m){
  int s = m ^ ((m>>3)&7) ^ ((m>>6)&7);
  return (r<<9) + (s ^ ((2*r)&15));
}

// (512,4): VGPR budget = floor(256/min_waves) = 64 (measured r1/r2). r6 spilled
// ~270MB of scratch because the fully-unrolled staging loop hoisted all 32
// loaded floats at once; this version rolls the loop (#pragma unroll 1) with
// explicit prefetch-by-one (max 16 floats in flight) and shrinks the window
// registers 4->2 via the Hann identity w[n+512] = 1-w[n]. Peak live ~58 regs.
__global__ __launch_bounds__(512,4) void istft_fused(
    const float* __restrict__ sr, const float* __restrict__ si,
    const float* __restrict__ win, float* __restrict__ out)
{
  __shared__ float2 zc[16*512];                    // 65536 B: frames T0..T0+15

  const int tid = threadIdx.x;
  // chunked XCD swizzle: dispatch d -> logical L so each XCD owns 148
  // CONSECUTIVE (b,tile) ids; straddled cache lines and the 4-frame tile
  // overlap are then re-read by same-XCD neighbors -> L2 hits, not HBM.
  const int d    = blockIdx.x;
  const int L    = (d & 7)*CPX + (d >> 3);
  const int b    = L / TILES;
  const int tile = L % TILES;
  const int Tbase= tile*FTO - 2;

  float2 acc[7];                                   // 7 output pairs per thread
  #pragma unroll
  for (int i=0;i<7;++i) acc[i]=make_float2(0.f,0.f);

  const int f  = tid & 7;                          // t-pair slot / frame slot
  const int pp = tid >> 3;                         // [0,64)
  const float* srb = sr + (size_t)b*NROW*TT;
  const float* sib = si + (size_t)b*NROW*TT;

  // Per-thread window registers: gather only touches m0 = r_w + 128*j, j=0..3.
  // Keep j=0,1 in regs; j=2,3 via Hann complement w[n+512] = 1 - w[n].
  const int r_w = (tid + 64) & 127;
  float2 wreg[2];
  #pragma unroll
  for (int j=0;j<2;++j) wreg[j] = ((const float2*)win)[r_w + 128*j];

  // build Z[row] entries for one frame (row in [0,16)) from spectrum row k
  auto storeZ = [&](int row, int k, float ar,float ai,float br,float bi,
                    float cr,float ci, float s_, float c_){
    if (k==0){
      zc[zidx(row,0)] = make_float2(0.5f*(ar+br), 0.5f*(ar-br));
      zc[zidx(row,1)] = make_float2(cr, -ci);      // brev9(256)=1, Z=conj(X[256])
    } else {
      float Er=0.5f*(ar+br), Ei=0.5f*(ai-bi);
      float Dr=0.5f*(ar-br), Di=0.5f*(ai+bi);
      float Or=Dr*c_-Di*s_, Oi=Dr*s_+Di*c_;
      zc[zidx(row,brev9(k))]     = make_float2(Er-Oi, Ei+Or);
      zc[zidx(row,brev9(512-k))] = make_float2(Er+Oi, Or-Ei);
    }
  };

  #pragma unroll 1
  for (int half=0; half<2; ++half){
    const int T0 = Tbase + 16*half;
    const int ta = T0 + 2*f;                       // even
    const int tp = min(max(ta,0),TT-2);            // clamped, even -> 8B aligned
    const float m0_ = (ta>=0   && ta  <TT)?(1.f/512.f):0.f;
    const float m1_ = (ta+1>=0 && ta+1<TT)?(1.f/512.f):0.f;
    const float* srt = srb + tp;
    const float* sit = sib + tp;

    __syncthreads();                               // zc WAR vs previous gather

    // X[256] (needed only by the k==0 storeZ path, pp==0 threads)
    float2 vRc=make_float2(0.f,0.f), vIc=make_float2(0.f,0.f);
    if (pp==0){
      vRc = *(const float2*)(srt + (size_t)256*TT);
      vIc = *(const float2*)(sit + (size_t)256*TT);
    }

    // rolled staging with prefetch-by-one: exactly one iteration's 4 float2
    // loads in flight ahead of the butterflies -> no mass load-hoisting.
    float2 cRk = *(const float2*)(srt + (size_t)pp*TT);
    float2 cIk = *(const float2*)(sit + (size_t)pp*TT);
    float2 cRq = *(const float2*)(srt + (size_t)(512-pp)*TT);
    float2 cIq = *(const float2*)(sit + (size_t)(512-pp)*TT);
    #pragma unroll 1
    for (int cc=0;cc<4;++cc){
      const int k = cc*64+pp;                      // [0,256)
      float2 nRk=cRk, nIk=cIk, nRq=cRq, nIq=cIq;
      if (cc<3){
        const int k2 = k+64;
        nRk = *(const float2*)(srt + (size_t)k2*TT);
        nIk = *(const float2*)(sit + (size_t)k2*TT);
        nRq = *(const float2*)(srt + (size_t)(512-k2)*TT);
        nIq = *(const float2*)(sit + (size_t)(512-k2)*TT);
      }
      float s_,c_; __sincosf((float)k*0.006135923151542565f,&s_,&c_);  // e^{i*pi*k/512}
      storeZ(2*f,   k, cRk.x*m0_, cIk.x*m0_, cRq.x*m0_, cIq.x*m0_, vRc.x*m0_, vIc.x*m0_, s_, c_);
      storeZ(2*f+1, k, cRk.y*m1_, cIk.y*m1_, cRq.y*m1_, cIq.y*m1_, vRc.y*m1_, vIc.y*m1_, s_, c_);
      cRk=nRk; cIk=nIk; cRq=nRq; cIq=nIq;
    }

    // 512-pt FFT on both 8-row chunks between the same barriers
    // (4 radix-4 stages + radix-2; twiddles on the fly, shared across chunks)
    #pragma unroll
    for (int st=0; st<4; ++st){
      __syncthreads();
      const int h = 1<<(2*st);
      #pragma unroll
      for (int i=0;i<2;++i){
        const int q   = pp + 64*i;                 // [0,128)
        const int ilo = q & (h-1);
        const int base= ((q>>(2*st))<<(2*st+2)) + ilo;
        float2 w1, w2;
        if (st==0){ w1=make_float2(1.f,0.f); w2=w1; }
        else {
          float s1,c1,s2,c2;
          __sincosf((float)(ilo<<(8-2*st))*0.012271846303085130f,&s1,&c1);
          __sincosf((float)(ilo<<(7-2*st))*0.012271846303085130f,&s2,&c2);
          w1=make_float2(c1,s1); w2=make_float2(c2,s2);
        }
        #pragma unroll
        for (int ch=0; ch<2; ++ch){
          const int r = ch*8 + f;
          float2 e0=zc[zidx(r,base)],     e1=zc[zidx(r,base+h)];
          float2 e2=zc[zidx(r,base+2*h)], e3=zc[zidx(r,base+3*h)];
          float t1r=e1.x*w1.x-e1.y*w1.y, t1i=e1.x*w1.y+e1.y*w1.x;
          float t3r=e3.x*w1.x-e3.y*w1.y, t3i=e3.x*w1.y+e3.y*w1.x;
          float arr=e0.x+t1r, ari=e0.y+t1i, brr=e0.x-t1r, bri=e0.y-t1i;
          float crr=e2.x+t3r, cri=e2.y+t3i, drr=e2.x-t3r, dri=e2.y-t3i;
          float cwr=crr*w2.x-cri*w2.y, cwi=crr*w2.y+cri*w2.x;
          float dwr=drr*w2.x-dri*w2.y, dwi=drr*w2.y+dri*w2.x;
          zc[zidx(r,base)]     = make_float2(arr+cwr, ari+cwi);
          zc[zidx(r,base+2*h)] = make_float2(arr-cwr, ari-cwi);
          zc[zidx(r,base+h)]   = make_float2(brr-dwi, bri+dwr);  // W^128=+i
          zc[zidx(r,base+3*h)] = make_float2(brr+dwi, bri-dwr);
        }
      }
    }
    __syncthreads();
    #pragma unroll
    for (int i=0;i<4;++i){                         // final radix-2, h=256
      const int q = pp + 64*i;                     // [0,256)
      float sq,cq; __sincosf((float)q*0.012271846303085130f,&sq,&cq);
      #pragma unroll
      for (int ch=0; ch<2; ++ch){
        const int r = ch*8 + f;
        float2 u = zc[zidx(r,q)], v = zc[zidx(r,q+256)];
        float tr=v.x*cq-v.y*sq, ti=v.x*sq+v.y*cq;
        zc[zidx(r,q)]     = make_float2(u.x+tr, u.y+ti);
        zc[zidx(r,q+256)] = make_float2(u.x-tr, u.y-ti);
      }
    }

    // merged register-gather OLA over all 16 staged frames.
    // m0 = base - 128*S with base = tid+512i+448-2048*half; base == r_w mod 128,
    // so m0 = r_w + 128*j and S = Sb - j, j=0..3 static. Window: wreg[j] for
    // j<2, 1-wreg[j-2] for j>=2 (Hann complement).
    __syncthreads();
    const int boff = 448 - 2048*half;
    #pragma unroll
    for (int i=0;i<7;++i){
      const int base = tid + 512*i + boff;
      const int Sb   = (base - r_w) >> 7;          // exact (base == r_w mod 128)
      #pragma unroll
      for (int j=0;j<4;++j){
        const int S = Sb - j;
        if (S >= 0 && S < 16){
          const int m0 = r_w + 128*j;              // [0,512)
          float2 v = zc[zidx(S,m0)];
          const float wx = (j<2)? wreg[j].x : 1.f - wreg[j-2].x;
          const float wy = (j<2)? wreg[j].y : 1.f - wreg[j-2].y;
          acc[i].x += v.x*wx;
          acc[i].y += v.y*wy;
        }
      }
    }
  }

  // ---- finalize from registers: env division (1.5 interior), float2 store ----
  const bool edge = (tile==0)|(tile==TILES-1);
  float* outb = out + (size_t)b*OUTLB;
  const int gbase = tile*SPAN;
  #pragma unroll
  for (int i=0;i<7;++i){
    int p0 = 2*(tid + 512*i);
    int gs = gbase + p0;
    if (gs < OUTLB){
      float2 r = acc[i];
      if (!edge){
        r.x *= (2.f/3.f); r.y *= (2.f/3.f);        // Hann 4x OLA env = 1.5
      } else {
        #pragma unroll
        for (int e=0;e<2;++e){
          int l = gbase + 384 + p0 + e;
          int j0 = l & 255, tb = l >> 8;
          float env=0.f;
          #pragma unroll
          for (int mm=0;mm<4;++mm){
            int t2 = tb-mm;
            if (t2>=0 && t2<TT){
              float wv = 0.5f-0.5f*__cosf((float)(j0+256*mm)*0.006135923151542565f);
              env += wv*wv;
            }
          }
          ((float*)&r)[e] /= env;
        }
      }
      *(float2*)(outb+gs) = r;
    }
  }
}

extern "C" void kernel_launch(void* const* d_in, const int* in_sizes, int n_in,
                              void* d_out, int out_size, void* d_ws, size_t ws_size,
                              hipStream_t stream) {
  const float* sr = (const float*)d_in[0];
  const float* si = (const float*)d_in[1];
  const float* w  = (const float*)d_in[2];
  float* out = (float*)d_out;
  istft_fused<<<NWG, 512, 0, stream>>>(sr, si, w, out);
}